// Round 11
// baseline (170.079 us; speedup 1.0000x reference)
//
#include <hip/hip_runtime.h>
#include <math.h>

// Problem constants
#define NQ   65536
#define H    32
#define IN   64
#define OUTC 64
#define K    15
#define QB   16          // queries per block
#define S_WT 36          // wT row stride
#define AK   72          // Awt k_kp stride (R4/R9/R10, 0 conflicts measured)
#define AROW 1076        // Awt per-query row stride (R4/R9/R10, 0 conflicts measured)
#define INV_EXT (1.0f / 0.048f)

// d_ws layout (bytes)
#define OFF_PSUM  131072                       // psum [2][64][4096] float = 2 MB
#define OFF_SCSH  (OFF_PSUM + 2097152)         // 128 floats
#define OFF_XBF   (OFF_SCSH + 1024)            // x in bf16: 8 MB
#define NEED_BF16 (OFF_XBF + (size_t)NQ * IN * 2)

typedef __attribute__((ext_vector_type(8))) short short8;
typedef __attribute__((ext_vector_type(4))) short short4v;
typedef __attribute__((ext_vector_type(4))) float float4v;

static __device__ __forceinline__ unsigned short f2bf(float f) {
    return (unsigned short)((__float_as_uint(f) + 0x8000u) >> 16);
}
static __device__ __forceinline__ unsigned pk2(float a, float b) {
    return (__float_as_uint(a) + 0x8000u) >> 16 |
           ((__float_as_uint(b) + 0x8000u) & 0xFFFF0000u);
}

// ---------------------------------------------------------------------------
// Prep: blocks [0,4096): x fp32 -> bf16 (coalesced).
//       blocks [4096,4336): W repack -> stage-2 B-frag dump order.
// ---------------------------------------------------------------------------
__global__ __launch_bounds__(256) void prep_all(
    const float* __restrict__ W, const float* __restrict__ x,
    short* __restrict__ Bfrag, unsigned short* __restrict__ xbf, int do_x)
{
    const int b = blockIdx.x;
    if (b < 4096) {
        if (do_x) {
            const int t = b * 256 + threadIdx.x;      // float4 index
            const float4 v = ((const float4*)x)[t];
            uint2 p; p.x = pk2(v.x, v.y); p.y = pk2(v.z, v.w);
            ((uint2*)xbf)[t] = p;
        }
    } else {
        const int t2 = (b - 4096) * 256 + threadIdx.x;   // flat W index, coalesced
        const int o  = t2 & 63;
        const int i  = (t2 >> 6) & 63;
        const int kq = t2 >> 12;                          // 0..14
        const int t  = kq * 2 + (i >> 5);
        const int lane = ((i >> 3) & 3) * 16 + (o & 15);
        const int v  = o >> 4;
        const int j  = i & 7;
        Bfrag[((v * 30 + t) * 64 + lane) * 8 + j] = (short)f2bf(W[t2]);
    }
}

// ---------------------------------------------------------------------------
// Main: stage 1 gathers B-fragments DIRECTLY into registers (no xn LDS, no
// scalar ds_read_u16). Lane (quad,ml) needs x[id(h=quad*8+j)][v*16+ml]:
// one 64-bit address per j + 4 u16 loads at immediate offsets 32/64/96 B.
// Double-buffered one query ahead. wT stays in LDS (wave-private slices).
// LDS: phase1 wT[16][16][36]=18432B; phase2 Awt[16][1076]=34432B (union).
// ---------------------------------------------------------------------------
template<bool BFX>
__global__ __launch_bounds__(256, 4) void kpconv_mfma(
    const float* __restrict__ x, const unsigned short* __restrict__ xbf,
    const float* __restrict__ qp, const float* __restrict__ sp,
    const int* __restrict__ inds, const float* __restrict__ kp,
    const short* __restrict__ Bfrag, float* __restrict__ out_raw,
    float* __restrict__ psum)
{
    __shared__ __align__(16) short lds[17216];            // 34432 B, 4 blk/CU
    short* wT  = lds;                                     // [16][16][S_WT]
    short* Awt = lds;                                     // phase 2 (union)

    const int tid  = threadIdx.x;
    const int lane = tid & 63;
    const int wv   = tid >> 6;
    const int quad = lane >> 4;
    const int ml   = lane & 15;
    const int q0   = blockIdx.x * QB;

    // ---- Prefetch query (wv*4+0)'s B-fragments (fly under stage A) ----
    short8 g0[4], g1[4];
    if (BFX) {
        const int ib = (q0 + wv * 4) * H + quad * 8;
#pragma unroll
        for (int j = 0; j < 8; ++j) {
            const int id = inds[ib + j];
            const unsigned short* p = xbf + id * IN + ml;
#pragma unroll
            for (int v = 0; v < 4; ++v) g0[v][j] = (short)p[v * 16];
        }
    }

    // ---- Stage A (wave-private): wT for this wave's 4 queries ----
    for (int rep = 0; rep < 2; ++rep) {
        const int p = lane + rep * 64;       // 0..127
        const int qi = p >> 5, h = p & 31;
        const int qg = wv * 4 + qi;
        const int n = q0 + qg;
        const int id = inds[n * H + h];
        const float dx = sp[id * 3 + 0] - qp[n * 3 + 0];
        const float dy = sp[id * 3 + 1] - qp[n * 3 + 1];
        const float dz = sp[id * 3 + 2] - qp[n * 3 + 2];
#pragma unroll
        for (int k = 0; k < K; ++k) {
            const float ex = dx - kp[k * 3 + 0];
            const float ey = dy - kp[k * 3 + 1];
            const float ez = dz - kp[k * 3 + 2];
            const float sq = ex * ex + ey * ey + ez * ez;
            float wval = 1.0f - __builtin_amdgcn_sqrtf(sq) * INV_EXT;
            wval = wval > 0.0f ? wval : 0.0f;
            wT[(qg * 16 + k) * S_WT + h] = (short)f2bf(wval);
        }
        wT[(qg * 16 + K) * S_WT + h] = 0;
    }
    // no barrier: wT rows for qg in [4wv,4wv+4) are read only by this wave

    // ---- Stage 1: register-gathered B-frags, no LDS traffic for x ----
    float4v frag[4][4];                      // [qi][n-tile v]
#pragma unroll
    for (int qi = 0; qi < 4; ++qi)
#pragma unroll
        for (int v = 0; v < 4; ++v) frag[qi][v] = (float4v){0.f, 0.f, 0.f, 0.f};

#pragma unroll
    for (int qi = 0; qi < 4; ++qi) {
        const int qg = wv * 4 + qi;

        short8* cur = (qi & 1) ? g1 : g0;
        short8* nxt = (qi & 1) ? g0 : g1;

        if (BFX) {
            // issue next query's 32 gathers (fly under this query's MFMAs)
            if (qi < 3) {
                const int ib = (q0 + qg + 1) * H + quad * 8;
#pragma unroll
                for (int j = 0; j < 8; ++j) {
                    const int id = inds[ib + j];
                    const unsigned short* p = xbf + id * IN + ml;
#pragma unroll
                    for (int v = 0; v < 4; ++v) nxt[v][j] = (short)p[v * 16];
                }
            }
        } else {
            // fallback (slow, correctness-only): direct fp32 gather + cvt
            const int ib = (q0 + qg) * H + quad * 8;
#pragma unroll
            for (int j = 0; j < 8; ++j) {
                const int id = inds[ib + j];
                const float* p = x + id * IN + ml;
#pragma unroll
                for (int v = 0; v < 4; ++v) cur[v][j] = (short)f2bf(p[v * 16]);
            }
        }

        // A-frag: per query, shared across the 4 n-tiles
        const int arow = (qg * 16 + ml) * S_WT + quad * 8;
        const short4v alo = *(const short4v*)&wT[arow];
        const short4v ahi = *(const short4v*)&wT[arow + 4];
        short8 a;
#pragma unroll
        for (int e = 0; e < 4; ++e) { a[e] = alo[e]; a[e + 4] = ahi[e]; }

        // 4 MFMAs: n-tiles 0..3 of this query (B straight from registers)
#pragma unroll
        for (int v = 0; v < 4; ++v)
            frag[qi][v] = __builtin_amdgcn_mfma_f32_16x16x32_bf16(a, cur[v], frag[qi][v], 0, 0, 0);
    }

    __syncthreads();   // all waves done with wT before Awt overwrites

    // ---- Round trip: C-frags -> Awt (stage-2 A layout, bf16) ----
#pragma unroll
    for (int qi = 0; qi < 4; ++qi) {
        const int qg = wv * 4 + qi;
#pragma unroll
        for (int v = 0; v < 4; ++v) {
#pragma unroll
            for (int r = 0; r < 4; ++r) {
                const int kq = quad * 4 + r;
                if (kq < K)
                    Awt[qg * AROW + kq * AK + v * 16 + ml] = (short)f2bf(frag[qi][v][r]);
            }
        }
    }
    __syncthreads();

    // ---- Stage 2: out[q][o] = sum_{k'} Awt[q][k'] * W'[k'][o] ----
    float4v acc = (float4v){0.f, 0.f, 0.f, 0.f};
    const short* bptr = Bfrag + (wv * 30) * 512 + lane * 8;
    short8 bcur = *(const short8*)(bptr);
#pragma unroll 2
    for (int t = 0; t < 30; ++t) {
        short8 bnxt = bcur;
        if (t < 29) bnxt = *(const short8*)(bptr + (t + 1) * 512);   // prefetch
        const int abase = ml * AROW + (t >> 1) * AK + (t & 1) * 32 + quad * 8;
        const short4v alo = *(const short4v*)&Awt[abase];
        const short4v ahi = *(const short4v*)&Awt[abase + 4];
        short8 a;
#pragma unroll
        for (int e = 0; e < 4; ++e) { a[e] = alo[e]; a[e + 4] = ahi[e]; }
        acc = __builtin_amdgcn_mfma_f32_16x16x32_bf16(a, bcur, acc, 0, 0, 0);
        bcur = bnxt;
    }

    // ---- Epilogue: write raw out + per-block channel sums (BN partials) ----
    float s = 0.f, s2 = 0.f;
#pragma unroll
    for (int r = 0; r < 4; ++r) {
        const float v = acc[r];
        out_raw[(q0 + quad * 4 + r) * OUTC + wv * 16 + ml] = v;
        s += v; s2 += v * v;
    }
    s  += __shfl_xor(s, 16, 64);  s  += __shfl_xor(s, 32, 64);
    s2 += __shfl_xor(s2, 16, 64); s2 += __shfl_xor(s2, 32, 64);
    if (quad == 0) {
        const int c = wv * 16 + ml;
        psum[c * 4096 + blockIdx.x]          = s;
        psum[262144 + c * 4096 + blockIdx.x] = s2;
    }
}

// ---------------------------------------------------------------------------
// BN stats: one block per channel, reduce 4096 partials -> scale/shift
// ---------------------------------------------------------------------------
__global__ __launch_bounds__(256) void bn_stats(
    const float* __restrict__ psum, const float* __restrict__ gamma,
    const float* __restrict__ beta, float* __restrict__ sc_sh)
{
    const int c = blockIdx.x;
    const int t = threadIdx.x;
    float s = 0.f, q = 0.f;
#pragma unroll
    for (int i = 0; i < 16; ++i) {
        s += psum[c * 4096 + t + i * 256];
        q += psum[262144 + c * 4096 + t + i * 256];
    }
    __shared__ float rs[4], rq[4];
#pragma unroll
    for (int off = 32; off; off >>= 1) {
        s += __shfl_down(s, off, 64);
        q += __shfl_down(q, off, 64);
    }
    if ((t & 63) == 0) { rs[t >> 6] = s; rq[t >> 6] = q; }
    __syncthreads();
    if (t == 0) {
        s = rs[0] + rs[1] + rs[2] + rs[3];
        q = rq[0] + rq[1] + rq[2] + rq[3];
        const float mean = s * (1.0f / (float)NQ);
        const float var  = q * (1.0f / (float)NQ) - mean * mean;
        const float scale = gamma[c] / sqrtf(var + 1e-5f);
        sc_sh[c]      = scale;
        sc_sh[64 + c] = beta[c] - mean * scale;
    }
}

// ---------------------------------------------------------------------------
// Apply BN + LeakyReLU(0.1) in place (float4)
// ---------------------------------------------------------------------------
__global__ __launch_bounds__(256) void bn_apply(
    float* __restrict__ out, const float* __restrict__ sc_sh)
{
    __shared__ float sc[64];
    __shared__ float sh[64];
    if (threadIdx.x < 64) {
        sc[threadIdx.x] = sc_sh[threadIdx.x];
        sh[threadIdx.x] = sc_sh[64 + threadIdx.x];
    }
    __syncthreads();
    const int idx = blockIdx.x * 256 + threadIdx.x;
#pragma unroll
    for (int it = 0; it < 4; ++it) {
        const int e = idx + it * 262144;
        float4 v = ((const float4*)out)[e];
        const int cg = (e & 15) * 4;
        float4 r;
        r.x = v.x * sc[cg + 0] + sh[cg + 0];
        r.y = v.y * sc[cg + 1] + sh[cg + 1];
        r.z = v.z * sc[cg + 2] + sh[cg + 2];
        r.w = v.w * sc[cg + 3] + sh[cg + 3];
        r.x = r.x >= 0.0f ? r.x : 0.1f * r.x;
        r.y = r.y >= 0.0f ? r.y : 0.1f * r.y;
        r.z = r.z >= 0.0f ? r.z : 0.1f * r.z;
        r.w = r.w >= 0.0f ? r.w : 0.1f * r.w;
        ((float4*)out)[e] = r;
    }
}

// ---------------------------------------------------------------------------
extern "C" void kernel_launch(void* const* d_in, const int* in_sizes, int n_in,
                              void* d_out, int out_size, void* d_ws, size_t ws_size,
                              hipStream_t stream)
{
    (void)in_sizes; (void)n_in; (void)out_size;
    const float* x     = (const float*)d_in[0];
    const float* qp    = (const float*)d_in[1];
    const float* sp    = (const float*)d_in[2];
    const int*   inds  = (const int*)d_in[3];
    const float* kp    = (const float*)d_in[4];
    const float* W     = (const float*)d_in[5];
    const float* gamma = (const float*)d_in[6];
    const float* beta  = (const float*)d_in[7];
    float* out = (float*)d_out;

    short*          Bfrag = (short*)d_ws;
    float*          psum  = (float*)((char*)d_ws + OFF_PSUM);
    float*          sc_sh = (float*)((char*)d_ws + OFF_SCSH);
    unsigned short* xbf   = (unsigned short*)((char*)d_ws + OFF_XBF);

    const int use_bf = (ws_size >= NEED_BF16) ? 1 : 0;

    prep_all<<<4336, 256, 0, stream>>>(W, x, Bfrag, xbf, use_bf);
    if (use_bf)
        kpconv_mfma<true><<<NQ / QB, 256, 0, stream>>>(x, xbf, qp, sp, inds, kp, Bfrag, out, psum);
    else
        kpconv_mfma<false><<<NQ / QB, 256, 0, stream>>>(x, xbf, qp, sp, inds, kp, Bfrag, out, psum);
    bn_stats<<<64, 256, 0, stream>>>(psum, gamma, beta, sc_sh);
    bn_apply<<<1024, 256, 0, stream>>>(out, sc_sh);
}

// Round 12
// 151.613 us; speedup vs baseline: 1.1218x; 1.1218x over previous
//
#include <hip/hip_runtime.h>
#include <math.h>

// Problem constants
#define NQ   65536
#define H    32
#define IN   64
#define OUTC 64
#define K    15
#define QB   16          // queries per block
#define S_XN 68          // xn row stride (bf16 elems), conflict-free (measured R4/R9/R10)
#define S_WT 36          // wT row stride
#define AK   72          // Awt k_kp stride (0 conflicts measured)
#define AROW 1076        // Awt per-query row stride (0 conflicts measured)
#define INV_EXT (1.0f / 0.048f)

// d_ws layout (bytes)
#define OFF_PSUM  131072                       // psum [2][64][4096] float = 2 MB
#define OFF_SCSH  (OFF_PSUM + 2097152)         // 128 floats
#define OFF_XBF   (OFF_SCSH + 1024)            // x in bf16: 8 MB
#define NEED_BF16 (OFF_XBF + (size_t)NQ * IN * 2)

typedef __attribute__((ext_vector_type(8))) short short8;
typedef __attribute__((ext_vector_type(4))) short short4v;
typedef __attribute__((ext_vector_type(4))) float float4v;

static __device__ __forceinline__ unsigned short f2bf(float f) {
    return (unsigned short)((__float_as_uint(f) + 0x8000u) >> 16);
}
static __device__ __forceinline__ unsigned pk2(float a, float b) {
    return (__float_as_uint(a) + 0x8000u) >> 16 |
           ((__float_as_uint(b) + 0x8000u) & 0xFFFF0000u);
}

// ---------------------------------------------------------------------------
// Prep: blocks [0,4096): x fp32 -> bf16 (coalesced).
//       blocks [4096,4336): W repack -> stage-2 B-frag dump order.
// ---------------------------------------------------------------------------
__global__ __launch_bounds__(256) void prep_all(
    const float* __restrict__ W, const float* __restrict__ x,
    short* __restrict__ Bfrag, unsigned short* __restrict__ xbf, int do_x)
{
    const int b = blockIdx.x;
    if (b < 4096) {
        if (do_x) {
            const int t = b * 256 + threadIdx.x;      // float4 index
            const float4 v = ((const float4*)x)[t];
            uint2 p; p.x = pk2(v.x, v.y); p.y = pk2(v.z, v.w);
            ((uint2*)xbf)[t] = p;
        }
    } else {
        const int t2 = (b - 4096) * 256 + threadIdx.x;   // flat W index, coalesced
        const int o  = t2 & 63;
        const int i  = (t2 >> 6) & 63;
        const int kq = t2 >> 12;                          // 0..14
        const int t  = kq * 2 + (i >> 5);
        const int lane = ((i >> 3) & 3) * 16 + (o & 15);
        const int v  = o >> 4;
        const int j  = i & 7;
        Bfrag[((v * 30 + t) * 64 + lane) * 8 + j] = (short)f2bf(W[t2]);
    }
}

// ---------------------------------------------------------------------------
// Main: R10 barrier-free body, ONE change: gather prefetch depth 1 -> 4.
// All 32 gather loads (4 queries x 8 rows) issued up front; stage A and the
// per-query LDS/MFMA work run under them. xv[4][8] is indexed only by fully
// unrolled loop vars (SROA-safe; no pointer selection -- R11 lesson).
// LDS: phase1 xn[4 waves][32][68]=17408B + wT[16][16][36]=18432B = 35840B;
// phase2 Awt[16][1076]=34432B (union).
// ---------------------------------------------------------------------------
template<bool BFX>
__global__ __launch_bounds__(256, 4) void kpconv_mfma(
    const float* __restrict__ x, const unsigned short* __restrict__ xbf,
    const float* __restrict__ qp, const float* __restrict__ sp,
    const int* __restrict__ inds, const float* __restrict__ kp,
    const short* __restrict__ Bfrag, float* __restrict__ out_raw,
    float* __restrict__ psum)
{
    __shared__ __align__(16) short lds[17920];            // 35840 B, 4 blk/CU
    short* xn  = lds;                                     // [4 waves][32][S_XN]
    short* wT  = lds + 8704;                              // [16][16][S_WT]
    short* Awt = lds;                                     // phase 2

    const int tid  = threadIdx.x;
    const int lane = tid & 63;
    const int wv   = tid >> 6;
    const int quad = lane >> 4;
    const int ml   = lane & 15;
    const int q0   = blockIdx.x * QB;

    short* xn_own = xn + wv * (H * S_XN);   // wave-private stage-1 buffer

    // ---- Prefetch ALL 4 queries' gathers (32 loads in flight) ----
    short4v xv[4][8];
    float4  xf[4][8];
#pragma unroll
    for (int qi = 0; qi < 4; ++qi) {
        const int ibase = (q0 + wv * 4 + qi) * H;
#pragma unroll
        for (int j = 0; j < 8; ++j) {
            const int id = inds[ibase + j * 4 + quad];
            if (BFX) xv[qi][j] = *(const short4v*)((const short*)xbf + id * IN + ml * 4);
            else     xf[qi][j] = *(const float4*)(x + id * IN + ml * 4);
        }
    }

    // ---- Stage A (wave-private): wT for this wave's 4 queries ----
    for (int rep = 0; rep < 2; ++rep) {
        const int p = lane + rep * 64;       // 0..127
        const int qi = p >> 5, h = p & 31;
        const int qg = wv * 4 + qi;
        const int n = q0 + qg;
        const int id = inds[n * H + h];
        const float dx = sp[id * 3 + 0] - qp[n * 3 + 0];
        const float dy = sp[id * 3 + 1] - qp[n * 3 + 1];
        const float dz = sp[id * 3 + 2] - qp[n * 3 + 2];
#pragma unroll
        for (int k = 0; k < K; ++k) {
            const float ex = dx - kp[k * 3 + 0];
            const float ey = dy - kp[k * 3 + 1];
            const float ez = dz - kp[k * 3 + 2];
            const float sq = ex * ex + ey * ey + ez * ez;
            float wval = 1.0f - __builtin_amdgcn_sqrtf(sq) * INV_EXT;
            wval = wval > 0.0f ? wval : 0.0f;
            wT[(qg * 16 + k) * S_WT + h] = (short)f2bf(wval);
        }
        wT[(qg * 16 + K) * S_WT + h] = 0;
    }
    // no barrier: wT rows for qg in [4wv,4wv+4) are read only by this wave

    // ---- Stage 1: barrier-free per-wave loop over own 4 queries ----
    float4v frag[4][4];                      // [qi][n-tile v]
#pragma unroll
    for (int qi = 0; qi < 4; ++qi)
#pragma unroll
        for (int v = 0; v < 4; ++v) frag[qi][v] = (float4v){0.f, 0.f, 0.f, 0.f};

#pragma unroll
    for (int qi = 0; qi < 4; ++qi) {
        const int qg = wv * 4 + qi;

        // write prefetched rows to wave-private xn (vmcnt(N) wait lands here)
#pragma unroll
        for (int j = 0; j < 8; ++j) {
            const int h = j * 4 + quad;
            if (BFX) {
                *(short4v*)&xn_own[h * S_XN + ml * 4] = xv[qi][j];
            } else {
                short4v p;
                p[0] = (short)f2bf(xf[qi][j].x); p[1] = (short)f2bf(xf[qi][j].y);
                p[2] = (short)f2bf(xf[qi][j].z); p[3] = (short)f2bf(xf[qi][j].w);
                *(short4v*)&xn_own[h * S_XN + ml * 4] = p;
            }
        }

        // A-frag: per query, shared across the 4 n-tiles (hoisted)
        const int arow = (qg * 16 + ml) * S_WT + quad * 8;
        const short4v alo = *(const short4v*)&wT[arow];
        const short4v ahi = *(const short4v*)&wT[arow + 4];
        short8 a;
#pragma unroll
        for (int e = 0; e < 4; ++e) { a[e] = alo[e]; a[e + 4] = ahi[e]; }

        // 4 MFMAs: n-tiles 0..3 of this query (wave-private LDS reads)
#pragma unroll
        for (int v = 0; v < 4; ++v) {
            short8 bb;
#pragma unroll
            for (int j = 0; j < 8; ++j)
                bb[j] = xn_own[(quad * 8 + j) * S_XN + v * 16 + ml];
            frag[qi][v] = __builtin_amdgcn_mfma_f32_16x16x32_bf16(a, bb, frag[qi][v], 0, 0, 0);
        }
    }

    __syncthreads();   // all waves done with xn/wT before Awt overwrites

    // ---- Round trip: C-frags -> Awt (stage-2 A layout, bf16) ----
#pragma unroll
    for (int qi = 0; qi < 4; ++qi) {
        const int qg = wv * 4 + qi;
#pragma unroll
        for (int v = 0; v < 4; ++v) {
#pragma unroll
            for (int r = 0; r < 4; ++r) {
                const int kq = quad * 4 + r;
                if (kq < K)
                    Awt[qg * AROW + kq * AK + v * 16 + ml] = (short)f2bf(frag[qi][v][r]);
            }
        }
    }
    __syncthreads();

    // ---- Stage 2: out[q][o] = sum_{k'} Awt[q][k'] * W'[k'][o] ----
    float4v acc = (float4v){0.f, 0.f, 0.f, 0.f};
    const short* bptr = Bfrag + (wv * 30) * 512 + lane * 8;
#pragma unroll 2
    for (int t = 0; t < 30; ++t) {
        const int abase = ml * AROW + (t >> 1) * AK + (t & 1) * 32 + quad * 8;
        const short4v alo = *(const short4v*)&Awt[abase];
        const short4v ahi = *(const short4v*)&Awt[abase + 4];
        short8 a;
#pragma unroll
        for (int e = 0; e < 4; ++e) { a[e] = alo[e]; a[e + 4] = ahi[e]; }
        const short8 bb = *(const short8*)(bptr + t * 512);
        acc = __builtin_amdgcn_mfma_f32_16x16x32_bf16(a, bb, acc, 0, 0, 0);
    }

    // ---- Epilogue: write raw out + per-block channel sums (BN partials) ----
    float s = 0.f, s2 = 0.f;
#pragma unroll
    for (int r = 0; r < 4; ++r) {
        const float v = acc[r];
        out_raw[(q0 + quad * 4 + r) * OUTC + wv * 16 + ml] = v;
        s += v; s2 += v * v;
    }
    s  += __shfl_xor(s, 16, 64);  s  += __shfl_xor(s, 32, 64);
    s2 += __shfl_xor(s2, 16, 64); s2 += __shfl_xor(s2, 32, 64);
    if (quad == 0) {
        const int c = wv * 16 + ml;
        psum[c * 4096 + blockIdx.x]          = s;
        psum[262144 + c * 4096 + blockIdx.x] = s2;
    }
}

// ---------------------------------------------------------------------------
// BN stats: one block per channel, reduce 4096 partials -> scale/shift
// ---------------------------------------------------------------------------
__global__ __launch_bounds__(256) void bn_stats(
    const float* __restrict__ psum, const float* __restrict__ gamma,
    const float* __restrict__ beta, float* __restrict__ sc_sh)
{
    const int c = blockIdx.x;
    const int t = threadIdx.x;
    float s = 0.f, q = 0.f;
#pragma unroll
    for (int i = 0; i < 16; ++i) {
        s += psum[c * 4096 + t + i * 256];
        q += psum[262144 + c * 4096 + t + i * 256];
    }
    __shared__ float rs[4], rq[4];
#pragma unroll
    for (int off = 32; off; off >>= 1) {
        s += __shfl_down(s, off, 64);
        q += __shfl_down(q, off, 64);
    }
    if ((t & 63) == 0) { rs[t >> 6] = s; rq[t >> 6] = q; }
    __syncthreads();
    if (t == 0) {
        s = rs[0] + rs[1] + rs[2] + rs[3];
        q = rq[0] + rq[1] + rq[2] + rq[3];
        const float mean = s * (1.0f / (float)NQ);
        const float var  = q * (1.0f / (float)NQ) - mean * mean;
        const float scale = gamma[c] / sqrtf(var + 1e-5f);
        sc_sh[c]      = scale;
        sc_sh[64 + c] = beta[c] - mean * scale;
    }
}

// ---------------------------------------------------------------------------
// Apply BN + LeakyReLU(0.1) in place (float4)
// ---------------------------------------------------------------------------
__global__ __launch_bounds__(256) void bn_apply(
    float* __restrict__ out, const float* __restrict__ sc_sh)
{
    __shared__ float sc[64];
    __shared__ float sh[64];
    if (threadIdx.x < 64) {
        sc[threadIdx.x] = sc_sh[threadIdx.x];
        sh[threadIdx.x] = sc_sh[64 + threadIdx.x];
    }
    __syncthreads();
    const int idx = blockIdx.x * 256 + threadIdx.x;
#pragma unroll
    for (int it = 0; it < 4; ++it) {
        const int e = idx + it * 262144;
        float4 v = ((const float4*)out)[e];
        const int cg = (e & 15) * 4;
        float4 r;
        r.x = v.x * sc[cg + 0] + sh[cg + 0];
        r.y = v.y * sc[cg + 1] + sh[cg + 1];
        r.z = v.z * sc[cg + 2] + sh[cg + 2];
        r.w = v.w * sc[cg + 3] + sh[cg + 3];
        r.x = r.x >= 0.0f ? r.x : 0.1f * r.x;
        r.y = r.y >= 0.0f ? r.y : 0.1f * r.y;
        r.z = r.z >= 0.0f ? r.z : 0.1f * r.z;
        r.w = r.w >= 0.0f ? r.w : 0.1f * r.w;
        ((float4*)out)[e] = r;
    }
}

// ---------------------------------------------------------------------------
extern "C" void kernel_launch(void* const* d_in, const int* in_sizes, int n_in,
                              void* d_out, int out_size, void* d_ws, size_t ws_size,
                              hipStream_t stream)
{
    (void)in_sizes; (void)n_in; (void)out_size;
    const float* x     = (const float*)d_in[0];
    const float* qp    = (const float*)d_in[1];
    const float* sp    = (const float*)d_in[2];
    const int*   inds  = (const int*)d_in[3];
    const float* kp    = (const float*)d_in[4];
    const float* W     = (const float*)d_in[5];
    const float* gamma = (const float*)d_in[6];
    const float* beta  = (const float*)d_in[7];
    float* out = (float*)d_out;

    short*          Bfrag = (short*)d_ws;
    float*          psum  = (float*)((char*)d_ws + OFF_PSUM);
    float*          sc_sh = (float*)((char*)d_ws + OFF_SCSH);
    unsigned short* xbf   = (unsigned short*)((char*)d_ws + OFF_XBF);

    const int use_bf = (ws_size >= NEED_BF16) ? 1 : 0;

    prep_all<<<4336, 256, 0, stream>>>(W, x, Bfrag, xbf, use_bf);
    if (use_bf)
        kpconv_mfma<true><<<NQ / QB, 256, 0, stream>>>(x, xbf, qp, sp, inds, kp, Bfrag, out, psum);
    else
        kpconv_mfma<false><<<NQ / QB, 256, 0, stream>>>(x, xbf, qp, sp, inds, kp, Bfrag, out, psum);
    bn_stats<<<64, 256, 0, stream>>>(psum, gamma, beta, sc_sh);
    bn_apply<<<1024, 256, 0, stream>>>(out, sc_sh);
}